// Round 2
// baseline (251.088 us; speedup 1.0000x reference)
//
#include <hip/hip_runtime.h>
#include <stdint.h>
#include <stddef.h>

#define H 512
#define XD 256
#define NCHLD 32768
#define NB 128              // children per block in main kernel
#define KT 32               // K per MFMA step
#define NKT (H / KT)        // 16 k-steps
#define NCT (NB / 16)       // 8 col-tiles (children) per block

typedef float f32x4 __attribute__((ext_vector_type(4)));
typedef _Float16 f16x8 __attribute__((ext_vector_type(8)));
typedef _Float16 f16x4 __attribute__((ext_vector_type(4)));

// ws layout (floats):
//   [0,512)     pre_f = w_f@x + b_f
//   [512,1024)  c_acc (atomic accumulation of sum_n fs*cs)
//   [1024,1536) h_sum
//   [1536,3072) iou logits (3*512)

__device__ __forceinline__ float sigm(float x) { return 1.0f / (1.0f + __expf(-x)); }

__device__ __forceinline__ f16x8 load_a_f16(const float* __restrict__ p) {
    float4 a = *(const float4*)p;
    float4 b = *(const float4*)(p + 4);
    f16x8 r;
    r[0] = (_Float16)a.x; r[1] = (_Float16)a.y; r[2] = (_Float16)a.z; r[3] = (_Float16)a.w;
    r[4] = (_Float16)b.x; r[5] = (_Float16)b.y; r[6] = (_Float16)b.z; r[7] = (_Float16)b.w;
    return r;
}

// k0: pre_f[h] = dot(w_f[h,:], x) + b_f[h]; zero c_acc, h_sum.
// grid 8 x 256; 4 threads per output row.
__global__ __launch_bounds__(256) void k0_setup(const float* __restrict__ x,
                                                const float* __restrict__ w_f,
                                                const float* __restrict__ b_f,
                                                float* __restrict__ ws) {
    const int gid = blockIdx.x * 256 + threadIdx.x;   // [0,2048)
    const int row = gid >> 2;
    const int part = gid & 3;
    const float4* wr = (const float4*)(w_f + (size_t)row * XD) + part * 16;
    const float4* xv = (const float4*)x + part * 16;
    float acc = 0.0f;
#pragma unroll 4
    for (int i = 0; i < 16; ++i) {
        float4 a = wr[i], b = xv[i];
        acc += a.x * b.x + a.y * b.y + a.z * b.z + a.w * b.w;
    }
    acc += __shfl_xor(acc, 1);
    acc += __shfl_xor(acc, 2);
    if (part == 0) {
        ws[row]        = acc + b_f[row];
        ws[512 + row]  = 0.0f;   // c_acc
        ws[1024 + row] = 0.0f;   // h_sum
    }
}

// k2: fused  fs = sigmoid(pre_f + u_f @ hs^T); c_acc += sum_n fs[:,n]*cs[n,:];
//     h_sum += per-block partial column sums of hs (computed from f32 staging loads).
// Block: 1024 threads = 16 waves; wave w owns rows [w*32, w*32+32) (2 MFMA row-tiles).
// Children tile: 128 per block, 8 col-tiles of 16. K staged in LDS fp16, double-buffered.
__global__ __launch_bounds__(1024) void k2_main(const float* __restrict__ hs,
                                                const float* __restrict__ cs,
                                                const float* __restrict__ u_f,
                                                float* __restrict__ ws) {
    __shared__ _Float16 hs_s[2][NB][KT];   // 16 KB
    __shared__ float hsum_l[H];            // 2 KB

    const float* pre_f  = ws;
    float* c_acc   = ws + 512;
    float* h_sum_g = ws + 1024;

    const int tid  = threadIdx.x;
    const int wid  = tid >> 6;
    const int lane = tid & 63;
    const int c0   = blockIdx.x * NB;

    if (tid < H) hsum_l[tid] = 0.0f;

    // staging: thread -> (child sc, k-group skg); one float4 of hs per k-step
    const int sc  = tid >> 3;      // 0..127
    const int skg = tid & 7;       // 0..7  (4 dims each)
    const float* hs_src = hs + (size_t)(c0 + sc) * H + skg * 4;

    f32x4 acc[2][NCT];
    const f32x4 vzero = {0.0f, 0.0f, 0.0f, 0.0f};
#pragma unroll
    for (int rt = 0; rt < 2; ++rt)
#pragma unroll
        for (int ct = 0; ct < NCT; ++ct)
            acc[rt][ct] = vzero;

    // A-fragment addressing: row = base + (lane&15), k = kk*32 + (lane>>4)*8 + j
    const int arow  = wid * 32 + (lane & 15);
    const int akgrp = (lane >> 4) * 8;
    const float* a0p = u_f + (size_t)arow * H + akgrp;
    const float* a1p = u_f + (size_t)(arow + 16) * H + akgrp;

    // B-fragment LDS addressing: col(child) = ct*16 + (lane&15), k_local = (lane>>4)*8 + j
    const int bcol = lane & 15;
    const int bk   = (lane >> 4) * 8;

    // ---- prologue: slice 0 ----
    float4 ld0 = *(const float4*)(hs_src);
    __syncthreads();   // hsum_l zeroing visible before atomics
    {
        float4 v = ld0;
#pragma unroll
        for (int m = 8; m <= 32; m <<= 1) {
            v.x += __shfl_xor(v.x, m);
            v.y += __shfl_xor(v.y, m);
            v.z += __shfl_xor(v.z, m);
            v.w += __shfl_xor(v.w, m);
        }
        if ((lane >> 3) == 0) {
            const int d = skg * 4;
            atomicAdd(&hsum_l[d + 0], v.x);
            atomicAdd(&hsum_l[d + 1], v.y);
            atomicAdd(&hsum_l[d + 2], v.z);
            atomicAdd(&hsum_l[d + 3], v.w);
        }
        f16x4 st;
        st[0] = (_Float16)ld0.x; st[1] = (_Float16)ld0.y;
        st[2] = (_Float16)ld0.z; st[3] = (_Float16)ld0.w;
        *(f16x4*)&hs_s[0][sc][skg * 4] = st;
    }
    __syncthreads();

    // ---- main K loop ----
    for (int kk = 0; kk < NKT; ++kk) {
        const int cur = kk & 1;
        const bool more = (kk + 1 < NKT);
        float4 nld;
        if (more) nld = *(const float4*)(hs_src + (size_t)(kk + 1) * KT);  // prefetch next slice

        f16x8 af0 = load_a_f16(a0p + (size_t)kk * KT);
        f16x8 af1 = load_a_f16(a1p + (size_t)kk * KT);
#pragma unroll
        for (int ct = 0; ct < NCT; ++ct) {
            f16x8 bf = *(const f16x8*)&hs_s[cur][ct * 16 + bcol][bk];
            acc[0][ct] = __builtin_amdgcn_mfma_f32_16x16x32_f16(af0, bf, acc[0][ct], 0, 0, 0);
            acc[1][ct] = __builtin_amdgcn_mfma_f32_16x16x32_f16(af1, bf, acc[1][ct], 0, 0, 0);
        }
        __syncthreads();           // all waves done reading hs_s[cur]
        if (more) {
            float4 v = nld;
#pragma unroll
            for (int m = 8; m <= 32; m <<= 1) {
                v.x += __shfl_xor(v.x, m);
                v.y += __shfl_xor(v.y, m);
                v.z += __shfl_xor(v.z, m);
                v.w += __shfl_xor(v.w, m);
            }
            if ((lane >> 3) == 0) {
                const int d = (kk + 1) * KT + skg * 4;
                atomicAdd(&hsum_l[d + 0], v.x);
                atomicAdd(&hsum_l[d + 1], v.y);
                atomicAdd(&hsum_l[d + 2], v.z);
                atomicAdd(&hsum_l[d + 3], v.w);
            }
            f16x4 st;
            st[0] = (_Float16)nld.x; st[1] = (_Float16)nld.y;
            st[2] = (_Float16)nld.z; st[3] = (_Float16)nld.w;
            *(f16x4*)&hs_s[cur ^ 1][sc][skg * 4] = st;
            __syncthreads();       // next slice visible
        }
    }

    // flush block-partial h_sum (all LDS atomics happened before the last barrier)
    if (tid < H) atomicAdd(&h_sum_g[tid], hsum_l[tid]);

    // ---- epilogue: sigmoid, multiply by cs, reduce over the 16 children of each col-tile ----
    const int g4 = (lane >> 4) * 4;
#pragma unroll
    for (int rt = 0; rt < 2; ++rt) {
        const int rbase = wid * 32 + rt * 16 + g4;          // 4 consecutive h-rows
        float4 pf = *(const float4*)(pre_f + rbase);
        f32x4 csum = vzero;
#pragma unroll
        for (int ct = 0; ct < NCT; ++ct) {
            const int child = c0 + ct * 16 + (lane & 15);
            float4 cv = *(const float4*)(cs + (size_t)child * H + rbase);
            csum[0] += sigm(acc[rt][ct][0] + pf.x) * cv.x;
            csum[1] += sigm(acc[rt][ct][1] + pf.y) * cv.y;
            csum[2] += sigm(acc[rt][ct][2] + pf.z) * cv.z;
            csum[3] += sigm(acc[rt][ct][3] + pf.w) * cv.w;
        }
#pragma unroll
        for (int m = 1; m <= 8; m <<= 1) {   // reduce over the 16-lane (child) group
            csum[0] += __shfl_xor(csum[0], m);
            csum[1] += __shfl_xor(csum[1], m);
            csum[2] += __shfl_xor(csum[2], m);
            csum[3] += __shfl_xor(csum[3], m);
        }
        if ((lane & 15) == 0) {
            atomicAdd(&c_acc[rbase + 0], csum[0]);
            atomicAdd(&c_acc[rbase + 1], csum[1]);
            atomicAdd(&c_acc[rbase + 2], csum[2]);
            atomicAdd(&c_acc[rbase + 3], csum[3]);
        }
    }
}

// k3: iou[g] = b_iou[g] + dot(w_iou[g,:], x) + dot(u_iou[g,:], h_sum); 4 threads/row.
__global__ __launch_bounds__(256) void k3_iou(const float* __restrict__ x,
                                              const float* __restrict__ w_iou,
                                              const float* __restrict__ u_iou,
                                              const float* __restrict__ b_iou,
                                              float* __restrict__ ws) {
    const int gid = blockIdx.x * 256 + threadIdx.x;   // [0,6144)
    const int row = gid >> 2;                          // [0,1536)
    const int part = gid & 3;
    const float* hsum = ws + 1024;
    float acc = 0.0f;
    const float4* wr = (const float4*)(w_iou + (size_t)row * XD) + part * 16;
    const float4* xv = (const float4*)x + part * 16;
#pragma unroll 4
    for (int i = 0; i < 16; ++i) {
        float4 a = wr[i], b = xv[i];
        acc += a.x * b.x + a.y * b.y + a.z * b.z + a.w * b.w;
    }
    const float4* ur = (const float4*)(u_iou + (size_t)row * H) + part * 32;
    const float4* hv = (const float4*)hsum + part * 32;
#pragma unroll 4
    for (int i = 0; i < 32; ++i) {
        float4 a = ur[i], b = hv[i];
        acc += a.x * b.x + a.y * b.y + a.z * b.z + a.w * b.w;
    }
    acc += __shfl_xor(acc, 1);
    acc += __shfl_xor(acc, 2);
    if (part == 0) ws[1536 + row] = acc + b_iou[row];
}

// k4: finalize c and h.
__global__ __launch_bounds__(512) void k4_fin(const float* __restrict__ ws,
                                              float* __restrict__ out) {
    const int h = threadIdx.x;
    const float iv = ws[1536 + h];
    const float ov = ws[1536 + 512 + h];
    const float uv = ws[1536 + 1024 + h];
    const float i = sigm(iv);
    const float o = sigm(ov);
    const float u = tanhf(uv);
    const float c = i * u + ws[512 + h];
    out[h]       = o * tanhf(c);
    out[512 + h] = c;
}

extern "C" void kernel_launch(void* const* d_in, const int* in_sizes, int n_in,
                              void* d_out, int out_size, void* d_ws, size_t ws_size,
                              hipStream_t stream) {
    const float* x     = (const float*)d_in[0];
    const float* hs    = (const float*)d_in[1];
    const float* cs    = (const float*)d_in[2];
    const float* w_iou = (const float*)d_in[3];
    const float* u_iou = (const float*)d_in[4];
    const float* b_iou = (const float*)d_in[5];
    const float* w_f   = (const float*)d_in[6];
    const float* u_f   = (const float*)d_in[7];
    const float* b_f   = (const float*)d_in[8];
    float* ws  = (float*)d_ws;
    float* out = (float*)d_out;

    k0_setup<<<8, 256, 0, stream>>>(x, w_f, b_f, ws);
    k2_main<<<NCHLD / NB, 1024, 0, stream>>>(hs, cs, u_f, ws);
    k3_iou<<<24, 256, 0, stream>>>(x, w_iou, u_iou, b_iou, ws);
    k4_fin<<<1, 512, 0, stream>>>(ws, out);
}

// Round 3
// 213.635 us; speedup vs baseline: 1.1753x; 1.1753x over previous
//
#include <hip/hip_runtime.h>
#include <stdint.h>
#include <stddef.h>

#define H 512
#define XD 256
#define NCHLD 32768
#define NB 64               // children per block
#define KT 32               // K per MFMA step
#define NKT 16              // H/KT k-steps
#define NCT 4               // col-tiles (children/16)
#define NRT 4               // row-tiles per wave (64 rows/wave * 8 waves = 512)
#define LDSP 40             // padded LDS pitch in f16 (80 B) -> conflict-free b128 reads
#define NSHARD 4

// ws layout (floats):
#define WS_PREF 0           // [512)   pre_f = w_f@x + b_f
#define WS_CACC 512         // [4][512] c_acc shards
#define WS_HSUM 2560        // [4][512] h_sum shards
#define WS_IOU  4608        // [3*512] iou logits
#define WS_UF16 8192        // u_f as f16, 262144 halves (131072 float slots)

typedef float f32x4 __attribute__((ext_vector_type(4)));
typedef _Float16 f16x8 __attribute__((ext_vector_type(8)));
typedef _Float16 f16x4 __attribute__((ext_vector_type(4)));

__device__ __forceinline__ float sigm(float x) { return 1.0f / (1.0f + __expf(-x)); }

// k0: (a) convert u_f -> f16 once (blocks 0..255); (b) pre_f = w_f@x + b_f and
// zero the c_acc/h_sum shards (blocks 256..263).
__global__ __launch_bounds__(256) void k0_setup(const float* __restrict__ x,
                                                const float* __restrict__ w_f,
                                                const float* __restrict__ b_f,
                                                const float* __restrict__ u_f,
                                                float* __restrict__ ws) {
    const int b = blockIdx.x;
    if (b < 256) {
        const int i = (b * 256 + threadIdx.x) * 4;
        float4 v = *(const float4*)(u_f + i);
        f16x4 h;
        h[0] = (_Float16)v.x; h[1] = (_Float16)v.y;
        h[2] = (_Float16)v.z; h[3] = (_Float16)v.w;
        *(f16x4*)((_Float16*)(ws + WS_UF16) + i) = h;
    } else {
        const int gid = (b - 256) * 256 + threadIdx.x;   // [0,2048)
        const int row = gid >> 2;
        const int part = gid & 3;
        const float4* wr = (const float4*)(w_f + (size_t)row * XD) + part * 16;
        const float4* xv = (const float4*)x + part * 16;
        float acc = 0.0f;
#pragma unroll 4
        for (int i = 0; i < 16; ++i) {
            float4 a = wr[i], c = xv[i];
            acc += a.x * c.x + a.y * c.y + a.z * c.z + a.w * c.w;
        }
        acc += __shfl_xor(acc, 1);
        acc += __shfl_xor(acc, 2);
        if (part == 0) ws[WS_PREF + row] = acc + b_f[row];
        ws[WS_CACC + gid] = 0.0f;    // 2048 = 4 shards * 512
        ws[WS_HSUM + gid] = 0.0f;
    }
}

// k2: fused fs = sigmoid(pre_f + u_f@hs^T), c_acc += sum_n fs*cs, h_sum partials.
// 512 thr / 8 waves, NB=64 children, grid 512 -> 2 blocks/CU. One barrier per k-step.
__global__ __launch_bounds__(512, 4) void k2_main(const float* __restrict__ hs,
                                                  const float* __restrict__ cs,
                                                  float* __restrict__ ws) {
    __shared__ _Float16 bt[2][NB][LDSP];   // 10.24 KB
    __shared__ float hsum_l[H];            // 2 KB

    const _Float16* uf16 = (const _Float16*)(ws + WS_UF16);
    const float* pre_f = ws + WS_PREF;
    float* c_acc = ws + WS_CACC + (blockIdx.x & (NSHARD - 1)) * H;
    float* h_sum = ws + WS_HSUM + (blockIdx.x & (NSHARD - 1)) * H;

    const int tid  = threadIdx.x;
    const int wid  = tid >> 6;
    const int lane = tid & 63;
    const int c0   = blockIdx.x * NB;

    // staging: thread -> (child sc, dim-group skg); one float4 of hs per k-step
    const int sc  = tid >> 3;     // 0..63
    const int skg = tid & 7;      // 0..7
    const float* hsrc = hs + (size_t)(c0 + sc) * H + skg * 4;
    _Float16* stp0 = &bt[0][sc][skg * 4];
    _Float16* stp1 = &bt[1][sc][skg * 4];

    // A fragments: row = wid*64 + rt*16 + (lane&15), k = kk*32 + (lane>>4)*8 + j
    const int arow = wid * 64 + (lane & 15);
    const int ak   = (lane >> 4) * 8;
    const _Float16* abase = uf16 + (size_t)arow * H + ak;

    // B fragments from LDS: child = ct*16 + (lane&15), k_local = (lane>>4)*8 + j
    const int bcol = lane & 15;
    const int bk   = (lane >> 4) * 8;

    f32x4 acc[NRT][NCT];
    const f32x4 vzero = {0.0f, 0.0f, 0.0f, 0.0f};
#pragma unroll
    for (int rt = 0; rt < NRT; ++rt)
#pragma unroll
        for (int ct = 0; ct < NCT; ++ct)
            acc[rt][ct] = vzero;

    if (tid < H) hsum_l[tid] = 0.0f;

    // issue-early: slices 0 and 1
    float4 ra = *(const float4*)(hsrc);
    float4 rb = *(const float4*)(hsrc + KT);
    __syncthreads();   // hsum_l zeroing visible

    {   // stage slice 0 -> buf0 + h_sum partial
        f16x4 h;
        h[0] = (_Float16)ra.x; h[1] = (_Float16)ra.y;
        h[2] = (_Float16)ra.z; h[3] = (_Float16)ra.w;
        *(f16x4*)stp0 = h;
        float4 v = ra;
#pragma unroll
        for (int m = 8; m <= 32; m <<= 1) {
            v.x += __shfl_xor(v.x, m); v.y += __shfl_xor(v.y, m);
            v.z += __shfl_xor(v.z, m); v.w += __shfl_xor(v.w, m);
        }
        if ((lane >> 3) == 0) {
            const int d = skg * 4;
            atomicAdd(&hsum_l[d + 0], v.x); atomicAdd(&hsum_l[d + 1], v.y);
            atomicAdd(&hsum_l[d + 2], v.z); atomicAdd(&hsum_l[d + 3], v.w);
        }
    }
    __syncthreads();

#pragma unroll
    for (int kk = 0; kk < NKT; ++kk) {
        if (kk + 2 < NKT) ra = *(const float4*)(hsrc + (size_t)(kk + 2) * KT);  // 2-ahead

        f16x8 af[NRT];
#pragma unroll
        for (int rt = 0; rt < NRT; ++rt)
            af[rt] = *(const f16x8*)(abase + (size_t)rt * 16 * H + kk * KT);

        const _Float16* bbase = &bt[kk & 1][0][0];
#pragma unroll
        for (int ct = 0; ct < NCT; ++ct) {
            f16x8 bf = *(const f16x8*)(bbase + (ct * 16 + bcol) * LDSP + bk);
#pragma unroll
            for (int rt = 0; rt < NRT; ++rt)
                acc[rt][ct] = __builtin_amdgcn_mfma_f32_16x16x32_f16(af[rt], bf, acc[rt][ct], 0, 0, 0);
        }

        if (kk + 1 < NKT) {   // write-late: stage slice kk+1 into the other buffer
            _Float16* stp = (kk & 1) ? stp0 : stp1;
            f16x4 h;
            h[0] = (_Float16)rb.x; h[1] = (_Float16)rb.y;
            h[2] = (_Float16)rb.z; h[3] = (_Float16)rb.w;
            *(f16x4*)stp = h;
            float4 v = rb;
#pragma unroll
            for (int m = 8; m <= 32; m <<= 1) {
                v.x += __shfl_xor(v.x, m); v.y += __shfl_xor(v.y, m);
                v.z += __shfl_xor(v.z, m); v.w += __shfl_xor(v.w, m);
            }
            if ((lane >> 3) == 0) {
                const int d = (kk + 1) * KT + skg * 4;
                atomicAdd(&hsum_l[d + 0], v.x); atomicAdd(&hsum_l[d + 1], v.y);
                atomicAdd(&hsum_l[d + 2], v.z); atomicAdd(&hsum_l[d + 3], v.w);
            }
        }
        __syncthreads();      // single barrier per step
        rb = ra;
    }

    if (tid < H) atomicAdd(&h_sum[tid], hsum_l[tid]);

    // epilogue: sigmoid, * cs, reduce over this block's 64 children
    const int g4 = (lane >> 4) * 4;
#pragma unroll
    for (int rt = 0; rt < NRT; ++rt) {
        const int rbase = wid * 64 + rt * 16 + g4;
        float4 pf = *(const float4*)(pre_f + rbase);
        f32x4 csum = vzero;
#pragma unroll
        for (int ct = 0; ct < NCT; ++ct) {
            const int child = c0 + ct * 16 + (lane & 15);
            float4 cv = *(const float4*)(cs + (size_t)child * H + rbase);
            csum[0] += sigm(acc[rt][ct][0] + pf.x) * cv.x;
            csum[1] += sigm(acc[rt][ct][1] + pf.y) * cv.y;
            csum[2] += sigm(acc[rt][ct][2] + pf.z) * cv.z;
            csum[3] += sigm(acc[rt][ct][3] + pf.w) * cv.w;
        }
#pragma unroll
        for (int m = 1; m <= 8; m <<= 1) {
            csum[0] += __shfl_xor(csum[0], m); csum[1] += __shfl_xor(csum[1], m);
            csum[2] += __shfl_xor(csum[2], m); csum[3] += __shfl_xor(csum[3], m);
        }
        if ((lane & 15) == 0) {
            atomicAdd(&c_acc[rbase + 0], csum[0]); atomicAdd(&c_acc[rbase + 1], csum[1]);
            atomicAdd(&c_acc[rbase + 2], csum[2]); atomicAdd(&c_acc[rbase + 3], csum[3]);
        }
    }
}

// k3: iou logits; 8 threads/row, 48 blocks; sums the 4 h_sum shards inline.
__global__ __launch_bounds__(256) void k3_iou(const float* __restrict__ x,
                                              const float* __restrict__ w_iou,
                                              const float* __restrict__ u_iou,
                                              const float* __restrict__ b_iou,
                                              float* __restrict__ ws) {
    const int gid = blockIdx.x * 256 + threadIdx.x;   // [0,12288)
    const int row = gid >> 3;                          // [0,1536)
    const int part = gid & 7;
    float acc = 0.0f;
    const float4* wr = (const float4*)(w_iou + (size_t)row * XD) + part * 8;
    const float4* xv = (const float4*)x + part * 8;
#pragma unroll
    for (int i = 0; i < 8; ++i) {
        float4 a = wr[i], b = xv[i];
        acc += a.x * b.x + a.y * b.y + a.z * b.z + a.w * b.w;
    }
    const float4* ur = (const float4*)(u_iou + (size_t)row * H) + part * 16;
    const float4* h0 = (const float4*)(ws + WS_HSUM) + part * 16;
    const float4* h1 = h0 + 128;
    const float4* h2 = h1 + 128;
    const float4* h3 = h2 + 128;
#pragma unroll 4
    for (int i = 0; i < 16; ++i) {
        float4 a = ur[i];
        float4 b0 = h0[i], b1 = h1[i], b2 = h2[i], b3 = h3[i];
        acc += a.x * (b0.x + b1.x + b2.x + b3.x);
        acc += a.y * (b0.y + b1.y + b2.y + b3.y);
        acc += a.z * (b0.z + b1.z + b2.z + b3.z);
        acc += a.w * (b0.w + b1.w + b2.w + b3.w);
    }
    acc += __shfl_xor(acc, 1);
    acc += __shfl_xor(acc, 2);
    acc += __shfl_xor(acc, 4);
    if (part == 0) ws[WS_IOU + row] = acc + b_iou[row];
}

// k4: finalize c and h (sums the 4 c_acc shards).
__global__ __launch_bounds__(512) void k4_fin(const float* __restrict__ ws,
                                              float* __restrict__ out) {
    const int h = threadIdx.x;
    const float i = sigm(ws[WS_IOU + h]);
    const float o = sigm(ws[WS_IOU + 512 + h]);
    const float u = tanhf(ws[WS_IOU + 1024 + h]);
    const float cacc = ws[WS_CACC + h] + ws[WS_CACC + 512 + h] +
                       ws[WS_CACC + 1024 + h] + ws[WS_CACC + 1536 + h];
    const float c = i * u + cacc;
    out[h]       = o * tanhf(c);
    out[512 + h] = c;
}

extern "C" void kernel_launch(void* const* d_in, const int* in_sizes, int n_in,
                              void* d_out, int out_size, void* d_ws, size_t ws_size,
                              hipStream_t stream) {
    const float* x     = (const float*)d_in[0];
    const float* hs    = (const float*)d_in[1];
    const float* cs    = (const float*)d_in[2];
    const float* w_iou = (const float*)d_in[3];
    const float* u_iou = (const float*)d_in[4];
    const float* b_iou = (const float*)d_in[5];
    const float* w_f   = (const float*)d_in[6];
    const float* u_f   = (const float*)d_in[7];
    const float* b_f   = (const float*)d_in[8];
    float* ws  = (float*)d_ws;
    float* out = (float*)d_out;

    k0_setup<<<264, 256, 0, stream>>>(x, w_f, b_f, u_f, ws);
    k2_main<<<NCHLD / NB, 512, 0, stream>>>(hs, cs, ws);
    k3_iou<<<48, 256, 0, stream>>>(x, w_iou, u_iou, b_iou, ws);
    k4_fin<<<1, 512, 0, stream>>>(ws, out);
}

// Round 4
// 209.312 us; speedup vs baseline: 1.1996x; 1.0207x over previous
//
#include <hip/hip_runtime.h>
#include <stdint.h>
#include <stddef.h>

#define H 512
#define XD 256
#define NCHLD 32768
#define NB 64               // children per block
#define NCT 4               // col-tiles (children/16)
#define NRT 4               // row-tiles per wave (64 rows/wave * 8 waves = 512)
#define LDSP 520            // LDS pitch in f16 (1040 B): b128 reads conflict-free
#define NSHARD 4

// ws layout (floats):
#define WS_PREF 0           // [512)   pre_f = w_f@x + b_f
#define WS_CACC 512         // [4][512] c_acc shards
#define WS_HSUM 2560        // [4][512] h_sum shards
#define WS_IOU  4608        // [3*512] iou logits
#define WS_UF16 8192        // u_f as f16, 262144 halves (131072 float slots)

typedef float f32x4 __attribute__((ext_vector_type(4)));
typedef _Float16 f16x8 __attribute__((ext_vector_type(8)));
typedef _Float16 f16x4 __attribute__((ext_vector_type(4)));

__device__ __forceinline__ float sigm(float x) { return 1.0f / (1.0f + __expf(-x)); }

// k0: (a) u_f -> f16 (blocks 0..255); (b) pre_f = w_f@x + b_f, zero shards (256..263).
__global__ __launch_bounds__(256) void k0_setup(const float* __restrict__ x,
                                                const float* __restrict__ w_f,
                                                const float* __restrict__ b_f,
                                                const float* __restrict__ u_f,
                                                float* __restrict__ ws) {
    const int b = blockIdx.x;
    if (b < 256) {
        const int i = (b * 256 + threadIdx.x) * 4;
        float4 v = *(const float4*)(u_f + i);
        f16x4 h;
        h[0] = (_Float16)v.x; h[1] = (_Float16)v.y;
        h[2] = (_Float16)v.z; h[3] = (_Float16)v.w;
        *(f16x4*)((_Float16*)(ws + WS_UF16) + i) = h;
    } else {
        const int gid = (b - 256) * 256 + threadIdx.x;   // [0,2048)
        const int row = gid >> 2;
        const int part = gid & 3;
        const float4* wr = (const float4*)(w_f + (size_t)row * XD) + part * 16;
        const float4* xv = (const float4*)x + part * 16;
        float acc = 0.0f;
#pragma unroll 4
        for (int i = 0; i < 16; ++i) {
            float4 a = wr[i], c = xv[i];
            acc += a.x * c.x + a.y * c.y + a.z * c.z + a.w * c.w;
        }
        acc += __shfl_xor(acc, 1);
        acc += __shfl_xor(acc, 2);
        if (part == 0) ws[WS_PREF + row] = acc + b_f[row];
        if (gid < 512) {   // zero 2048 floats of each shard array via float4
            ((float4*)(ws + WS_CACC))[gid] = make_float4(0.f, 0.f, 0.f, 0.f);
            ((float4*)(ws + WS_HSUM))[gid] = make_float4(0.f, 0.f, 0.f, 0.f);
        }
    }
}

// k2: whole 64x512 hs tile staged once in LDS (f16), ONE barrier, barrier-free K-loop.
// 512 thr / 8 waves; grid 512 -> 2 blocks/CU (LDS 67.1 KB/block).
__global__ __launch_bounds__(512, 4) void k2_main(const float* __restrict__ hs,
                                                  const float* __restrict__ cs,
                                                  float* __restrict__ ws) {
    __shared__ _Float16 bt[NB][LDSP];   // 66,560 B
    __shared__ float hsum_l[H];         // 2 KB

    const _Float16* uf16 = (const _Float16*)(ws + WS_UF16);
    const float* pre_f = ws + WS_PREF;
    float* c_acc = ws + WS_CACC + (blockIdx.x & (NSHARD - 1)) * H;
    float* h_sum = ws + WS_HSUM + (blockIdx.x & (NSHARD - 1)) * H;

    const int tid  = threadIdx.x;
    const int wid  = tid >> 6;
    const int lane = tid & 63;
    const int c0   = blockIdx.x * NB;

    // staging map: thread -> (child sc = tid>>3, dim-slot sg = tid&7);
    // slice s covers dims s*32 + sg*4 .. +4  (16 slices = full 512 dims)
    const int sc = tid >> 3;
    const int sg = tid & 7;
    const float* hsrc = hs + (size_t)(c0 + sc) * H + sg * 4;
    _Float16* stp = &bt[sc][sg * 4];

    if (tid < H) hsum_l[tid] = 0.0f;
    __syncthreads();

    // ---- staging phase: 16 slices, loads overlapped in batches of 8 ----
    float4 r[8];
#pragma unroll
    for (int s = 0; s < 8; ++s) r[s] = *(const float4*)(hsrc + (size_t)s * 32);

#define STAGE_SLICE(vv, s)                                                        \
    {                                                                             \
        f16x4 hq;                                                                 \
        hq[0] = (_Float16)(vv).x; hq[1] = (_Float16)(vv).y;                       \
        hq[2] = (_Float16)(vv).z; hq[3] = (_Float16)(vv).w;                       \
        *(f16x4*)(stp + (s) * 32) = hq;                                           \
        float4 v = (vv);                                                          \
        v.x += __shfl_xor(v.x, 8);  v.y += __shfl_xor(v.y, 8);                    \
        v.z += __shfl_xor(v.z, 8);  v.w += __shfl_xor(v.w, 8);                    \
        v.x += __shfl_xor(v.x, 16); v.y += __shfl_xor(v.y, 16);                   \
        v.z += __shfl_xor(v.z, 16); v.w += __shfl_xor(v.w, 16);                   \
        v.x += __shfl_xor(v.x, 32); v.y += __shfl_xor(v.y, 32);                   \
        v.z += __shfl_xor(v.z, 32); v.w += __shfl_xor(v.w, 32);                   \
        if (lane < 8) {                                                           \
            const int d = (s) * 32 + sg * 4;                                      \
            atomicAdd(&hsum_l[d + 0], v.x); atomicAdd(&hsum_l[d + 1], v.y);       \
            atomicAdd(&hsum_l[d + 2], v.z); atomicAdd(&hsum_l[d + 3], v.w);       \
        }                                                                         \
    }

#pragma unroll
    for (int s = 0; s < 8; ++s) {
        float4 vv = r[s];
        r[s] = *(const float4*)(hsrc + (size_t)(s + 8) * 32);   // issue batch 1
        STAGE_SLICE(vv, s)
    }
#pragma unroll
    for (int s = 0; s < 8; ++s) {
        STAGE_SLICE(r[s], s + 8)
    }
#undef STAGE_SLICE

    __syncthreads();   // the ONLY barrier: tile + hsum_l complete

    // flush per-block h_sum partial (overlaps with K-loop issue)
    atomicAdd(&h_sum[tid], hsum_l[tid]);

    // ---- barrier-free K-loop ----
    f32x4 acc[NRT][NCT];
    const f32x4 vzero = {0.0f, 0.0f, 0.0f, 0.0f};
#pragma unroll
    for (int rt = 0; rt < NRT; ++rt)
#pragma unroll
        for (int ct = 0; ct < NCT; ++ct)
            acc[rt][ct] = vzero;

    // A: row = wid*64 + rt*16 + (lane&15), k = kk*32 + (lane>>4)*8 + j
    const int arow = wid * 64 + (lane & 15);
    const int ak   = (lane >> 4) * 8;
    const _Float16* abase = uf16 + (size_t)arow * H + ak;
    // B: child = ct*16 + (lane&15), k_local = (lane>>4)*8 + j
    const int bcol = lane & 15;
    const int bk   = (lane >> 4) * 8;

#pragma unroll
    for (int kk = 0; kk < 16; ++kk) {
        f16x8 af[NRT];
#pragma unroll
        for (int rt = 0; rt < NRT; ++rt)
            af[rt] = *(const f16x8*)(abase + (size_t)rt * 16 * H + kk * 32);
#pragma unroll
        for (int ct = 0; ct < NCT; ++ct) {
            f16x8 bf = *(const f16x8*)(&bt[ct * 16 + bcol][kk * 32 + bk]);
#pragma unroll
            for (int rt = 0; rt < NRT; ++rt)
                acc[rt][ct] = __builtin_amdgcn_mfma_f32_16x16x32_f16(af[rt], bf, acc[rt][ct], 0, 0, 0);
        }
    }

    // ---- epilogue: sigmoid, * cs, reduce over the block's 64 children ----
    const int g4 = (lane >> 4) * 4;
#pragma unroll
    for (int rt = 0; rt < NRT; ++rt) {
        const int rbase = wid * 64 + rt * 16 + g4;
        float4 pf = *(const float4*)(pre_f + rbase);
        f32x4 csum = vzero;
#pragma unroll
        for (int ct = 0; ct < NCT; ++ct) {
            const int child = c0 + ct * 16 + (lane & 15);
            float4 cv = *(const float4*)(cs + (size_t)child * H + rbase);
            csum[0] += sigm(acc[rt][ct][0] + pf.x) * cv.x;
            csum[1] += sigm(acc[rt][ct][1] + pf.y) * cv.y;
            csum[2] += sigm(acc[rt][ct][2] + pf.z) * cv.z;
            csum[3] += sigm(acc[rt][ct][3] + pf.w) * cv.w;
        }
#pragma unroll
        for (int m = 1; m <= 8; m <<= 1) {
            csum[0] += __shfl_xor(csum[0], m); csum[1] += __shfl_xor(csum[1], m);
            csum[2] += __shfl_xor(csum[2], m); csum[3] += __shfl_xor(csum[3], m);
        }
        if ((lane & 15) == 0) {
            atomicAdd(&c_acc[rbase + 0], csum[0]); atomicAdd(&c_acc[rbase + 1], csum[1]);
            atomicAdd(&c_acc[rbase + 2], csum[2]); atomicAdd(&c_acc[rbase + 3], csum[3]);
        }
    }
}

// k3: iou logits; 16 threads/row, 96 blocks; sums the 4 h_sum shards inline.
__global__ __launch_bounds__(256) void k3_iou(const float* __restrict__ x,
                                              const float* __restrict__ w_iou,
                                              const float* __restrict__ u_iou,
                                              const float* __restrict__ b_iou,
                                              float* __restrict__ ws) {
    const int gid = blockIdx.x * 256 + threadIdx.x;   // [0,24576)
    const int row = gid >> 4;                          // [0,1536)
    const int part = gid & 15;
    float acc = 0.0f;
    const float4* wr = (const float4*)(w_iou + (size_t)row * XD) + part * 4;
    const float4* xv = (const float4*)x + part * 4;
#pragma unroll
    for (int i = 0; i < 4; ++i) {
        float4 a = wr[i], b = xv[i];
        acc += a.x * b.x + a.y * b.y + a.z * b.z + a.w * b.w;
    }
    const float4* ur = (const float4*)(u_iou + (size_t)row * H) + part * 8;
    const float4* h0 = (const float4*)(ws + WS_HSUM) + part * 8;
    const float4* h1 = h0 + 128;
    const float4* h2 = h1 + 128;
    const float4* h3 = h2 + 128;
#pragma unroll
    for (int i = 0; i < 8; ++i) {
        float4 a = ur[i];
        float4 b0 = h0[i], b1 = h1[i], b2 = h2[i], b3 = h3[i];
        acc += a.x * (b0.x + b1.x + b2.x + b3.x);
        acc += a.y * (b0.y + b1.y + b2.y + b3.y);
        acc += a.z * (b0.z + b1.z + b2.z + b3.z);
        acc += a.w * (b0.w + b1.w + b2.w + b3.w);
    }
    acc += __shfl_xor(acc, 1);
    acc += __shfl_xor(acc, 2);
    acc += __shfl_xor(acc, 4);
    acc += __shfl_xor(acc, 8);
    if (part == 0) ws[WS_IOU + row] = acc + b_iou[row];
}

// k4: finalize c and h (sums the 4 c_acc shards).
__global__ __launch_bounds__(512) void k4_fin(const float* __restrict__ ws,
                                              float* __restrict__ out) {
    const int h = threadIdx.x;
    const float i = sigm(ws[WS_IOU + h]);
    const float o = sigm(ws[WS_IOU + 512 + h]);
    const float u = tanhf(ws[WS_IOU + 1024 + h]);
    const float cacc = ws[WS_CACC + h] + ws[WS_CACC + 512 + h] +
                       ws[WS_CACC + 1024 + h] + ws[WS_CACC + 1536 + h];
    const float c = i * u + cacc;
    out[h]       = o * tanhf(c);
    out[512 + h] = c;
}

extern "C" void kernel_launch(void* const* d_in, const int* in_sizes, int n_in,
                              void* d_out, int out_size, void* d_ws, size_t ws_size,
                              hipStream_t stream) {
    const float* x     = (const float*)d_in[0];
    const float* hs    = (const float*)d_in[1];
    const float* cs    = (const float*)d_in[2];
    const float* w_iou = (const float*)d_in[3];
    const float* u_iou = (const float*)d_in[4];
    const float* b_iou = (const float*)d_in[5];
    const float* w_f   = (const float*)d_in[6];
    const float* u_f   = (const float*)d_in[7];
    const float* b_f   = (const float*)d_in[8];
    float* ws  = (float*)d_ws;
    float* out = (float*)d_out;

    k0_setup<<<264, 256, 0, stream>>>(x, w_f, b_f, u_f, ws);
    k2_main<<<NCHLD / NB, 512, 0, stream>>>(hs, cs, ws);
    k3_iou<<<96, 256, 0, stream>>>(x, w_iou, u_iou, b_iou, ws);
    k4_fin<<<1, 512, 0, stream>>>(ws, out);
}